// Round 8
// baseline (96.427 us; speedup 1.0000x reference)
//
#include <hip/hip_runtime.h>
#include <hip/hip_bf16.h>

// N=2048, D=768, H=12, Y=64. W = [Wq;Wk] as [1536][768] bf16 (Wq pre-scaled).
#define NN 2048
#define DD 768
#define HH 12
#define HW 1536
#define G_ELEMS (NN*DD)           // 1572864
#define W1_ELEMS (HH*64*DD)       // 589824
#define SPLITS 4
#define KPW (NN/SPLITS)           // 512 k-rows per split
#define NCH (KPW/64)              // 8 chunks per split
#define NROWS (HH*NN)             // 24576 (h,q) rows

typedef __attribute__((ext_vector_type(8))) short bf16x8;
typedef __attribute__((ext_vector_type(4))) float f32x4;

// native v_exp_f32 / v_log_f32 (both base-2).
__device__ __forceinline__ float exp2g(float x) { return __builtin_amdgcn_exp2f(x); }
__device__ __forceinline__ float log2g(float x) { return __builtin_amdgcn_logf(x); }

// beta*log2(e) = 0.125*1.4426950408889634 folded into Wq -> scores in base-2.
#define QSCALE 0.18033688011112042f

// ---------------- Kernel 1: fp32 -> bf16 convert (+ zero out) ----------------
// (R0-verbatim, absmax-0.0-proven.) Rationale for a SEPARATE convert pass:
// fused-fp32 staging doubles proj's L2 bytes; at the 128x64 tile that is
// 226 MB vs 75 MB bf16 — the 126 MB saving (~3.7us at 34.5 TB/s L2) beats
// the extra launch (~1.5-2us). At 64x64 (R0 vs R2) it was a wash; tile size
// flips the tradeoff.
__global__ __launch_bounds__(256) void convert_kernel(
    const float* __restrict__ g, const float* __restrict__ Wq,
    const float* __restrict__ Wk, __hip_bfloat16* __restrict__ gB,
    __hip_bfloat16* __restrict__ wB, float* __restrict__ out) {
  if (blockIdx.x == 0 && threadIdx.x == 0) out[0] = 0.0f;  // kills memset dispatch
  int base = (blockIdx.x * 256 + threadIdx.x) * 4;
  float4 v;
  __hip_bfloat16* dst;
  if (base < G_ELEMS) {
    v = *reinterpret_cast<const float4*>(g + base);
    dst = gB + base;
  } else if (base < G_ELEMS + W1_ELEMS) {
    int o = base - G_ELEMS;
    v = *reinterpret_cast<const float4*>(Wq + o);
    v.x *= QSCALE; v.y *= QSCALE; v.z *= QSCALE; v.w *= QSCALE;
    dst = wB + o;
  } else {
    int o = base - (G_ELEMS + W1_ELEMS);
    v = *reinterpret_cast<const float4*>(Wk + o);
    dst = wB + W1_ELEMS + o;
  }
  __hip_bfloat16 h0 = __float2bfloat16(v.x), h1 = __float2bfloat16(v.y);
  __hip_bfloat16 h2 = __float2bfloat16(v.z), h3 = __float2bfloat16(v.w);
  ushort4 u;
  u.x = *reinterpret_cast<unsigned short*>(&h0);
  u.y = *reinterpret_cast<unsigned short*>(&h1);
  u.z = *reinterpret_cast<unsigned short*>(&h2);
  u.w = *reinterpret_cast<unsigned short*>(&h3);
  *reinterpret_cast<ushort4*>(dst) = u;
}

// ---------------- Kernel 2: QK projection GEMM, bf16-staged ------------------
// C[2048][1536] = gB[2048][768] * wB[1536][768]^T.
// 128x64 tile (R4's measured-optimal geometry: 384 blocks, 1.5 blocks/CU;
// do NOT shrink block count — R6's 192 blocks regressed +8.4us on occupancy),
// but staging bf16 (75 MB L2 traffic vs R4's fused-fp32 226 MB).
// BK=64, double-buffered, 1 barrier/kt. XCD-contiguous swizzle: each XCD owns
// 2 bm-rows (768 KB of gB, L2-resident) x all 24 bn.
#define LDP 72   // 64 + 8 pad -> 2-way max on frag reads (free, m136)
__global__ __launch_bounds__(256) void proj_kernel(
    const __hip_bfloat16* __restrict__ gB, const __hip_bfloat16* __restrict__ wB,
    __hip_bfloat16* __restrict__ QK) {
  __shared__ __align__(16) __hip_bfloat16 As[2][128 * LDP];   // 36.9 KB
  __shared__ __align__(16) __hip_bfloat16 Bs[2][64 * LDP];    // 18.4 KB
  const int t = threadIdx.x;
  const int wave = t >> 6, lane = t & 63;
  const int lr = lane & 15, lg = lane >> 4;
  const int wm = wave & 1, wn = wave >> 1;     // wave -> (64-row half, 32-col half)
  const int bid = blockIdx.x;
  const int swz = (bid & 7) * 48 + (bid >> 3); // 8 XCDs x 48 contiguous blocks
  const int bm = swz / 24, bn = swz % 24;      // bm 0..15 (128 rows), bn 0..23 (64 cols)
  const int rr = t >> 3, ss = (t & 7) * 8;     // staging: 32 rows x 64 cols per unit

  const __hip_bfloat16* ga = gB + (bm * 128 + rr) * DD + ss;  // A units: +u*32*DD, u=0..3
  const __hip_bfloat16* gb = wB + (bn * 64 + rr) * DD + ss;   // B units: +u*32*DD, u=0..1

  f32x4 acc[4][2] = {};

  // prologue: stage kt=0 (bf16 16B loads, no cvt)
  {
#pragma unroll
    for (int u = 0; u < 4; ++u)
      *reinterpret_cast<uint4*>(&As[0][(rr + u * 32) * LDP + ss]) =
          *reinterpret_cast<const uint4*>(ga + u * 32 * DD);
#pragma unroll
    for (int u = 0; u < 2; ++u)
      *reinterpret_cast<uint4*>(&Bs[0][(rr + u * 32) * LDP + ss]) =
          *reinterpret_cast<const uint4*>(gb + u * 32 * DD);
  }
  __syncthreads();

  for (int it = 0; it < 12; ++it) {
    const int cur = it & 1;
    uint4 na[4], nb[2];
    if (it < 11) {
      const int kt = (it + 1) * 64;
#pragma unroll
      for (int u = 0; u < 4; ++u)
        na[u] = *reinterpret_cast<const uint4*>(ga + u * 32 * DD + kt);
#pragma unroll
      for (int u = 0; u < 2; ++u)
        nb[u] = *reinterpret_cast<const uint4*>(gb + u * 32 * DD + kt);
    }
#pragma unroll
    for (int ks = 0; ks < 2; ++ks) {
      bf16x8 a[4], b[2];
#pragma unroll
      for (int mt = 0; mt < 4; ++mt)
        a[mt] = *reinterpret_cast<const bf16x8*>(&As[cur][(wm * 64 + mt * 16 + lr) * LDP + ks * 32 + lg * 8]);
#pragma unroll
      for (int nt = 0; nt < 2; ++nt)
        b[nt] = *reinterpret_cast<const bf16x8*>(&Bs[cur][(wn * 32 + nt * 16 + lr) * LDP + ks * 32 + lg * 8]);
#pragma unroll
      for (int mt = 0; mt < 4; ++mt)
#pragma unroll
        for (int nt = 0; nt < 2; ++nt)
          acc[mt][nt] = __builtin_amdgcn_mfma_f32_16x16x32_bf16(a[mt], b[nt], acc[mt][nt], 0, 0, 0);
    }
    if (it < 11) {
#pragma unroll
      for (int u = 0; u < 4; ++u)
        *reinterpret_cast<uint4*>(&As[cur ^ 1][(rr + u * 32) * LDP + ss]) = na[u];
#pragma unroll
      for (int u = 0; u < 2; ++u)
        *reinterpret_cast<uint4*>(&Bs[cur ^ 1][(rr + u * 32) * LDP + ss]) = nb[u];
      __syncthreads();
    }
  }
#pragma unroll
  for (int mt = 0; mt < 4; ++mt) {
    int row = bm * 128 + wm * 64 + mt * 16 + lg * 4;
#pragma unroll
    for (int nt = 0; nt < 2; ++nt) {
      int col = bn * 64 + wn * 32 + nt * 16 + lr;
#pragma unroll
      for (int r = 0; r < 4; ++r)
        QK[(row + r) * HW + col] = __float2bfloat16(acc[mt][nt][r]);
    }
  }
}

// ---------------- Kernel 3: scores + per-lane online LSE, dbuf K in LDS ------
// (verbatim R2/R4: LDS staging loads each 8KB K-chunk ONCE per block fully
// coalesced, shared by 4 waves. No device fences — R3's per-block __threadfence
// caused a ~45us L2-writeback storm.)
// grid (16 q-tiles of 128, 12 heads, 4 k-splits) = 768 blocks (3/CU).
#define LDA 72
__global__ __launch_bounds__(256) void attn_kernel(
    const __hip_bfloat16* __restrict__ QK, float2* __restrict__ part) {
  __shared__ __align__(16) __hip_bfloat16 Ks[2][64 * LDA];
  const int t = threadIdx.x;
  const int wave = t >> 6, lane = t & 63;
  const int lr = lane & 15, lg = lane >> 4;
  const int q0 = blockIdx.x * 128, h = blockIdx.y, sp = blockIdx.z;
  const int k0 = sp * KPW;
  const int r0 = t >> 3, s0 = (t & 7) * 8;            // chunk coords (2/thread)
  const int r1 = (t + 256) >> 3, s1 = s0;
  const int colK = DD + h * 64;

  // Q fragments: 4 direct loads, resident for the whole kernel
  bf16x8 aq[2][2];
#pragma unroll
  for (int mt = 0; mt < 2; ++mt)
#pragma unroll
    for (int z = 0; z < 2; ++z)
      aq[mt][z] = *reinterpret_cast<const bf16x8*>(
          QK + (q0 + wave * 32 + mt * 16 + lr) * HW + h * 64 + z * 32 + lg * 8);

  // prologue: stage chunk 0
  *reinterpret_cast<uint4*>(&Ks[0][r0 * LDA + s0]) =
      *reinterpret_cast<const uint4*>(QK + (k0 + r0) * HW + colK + s0);
  *reinterpret_cast<uint4*>(&Ks[0][r1 * LDA + s1]) =
      *reinterpret_cast<const uint4*>(QK + (k0 + r1) * HW + colK + s1);
  __syncthreads();

  float m[2][4], l[2][4];
#pragma unroll
  for (int mt = 0; mt < 2; ++mt)
#pragma unroll
    for (int r = 0; r < 4; ++r) { m[mt][r] = -3.0e38f; l[mt][r] = 0.0f; }

  for (int ci = 0; ci < NCH; ++ci) {
    const int cur = ci & 1;
    uint4 n0, n1;
    if (ci < NCH - 1) {
      int kc = k0 + (ci + 1) * 64;
      n0 = *reinterpret_cast<const uint4*>(QK + (kc + r0) * HW + colK + s0);
      n1 = *reinterpret_cast<const uint4*>(QK + (kc + r1) * HW + colK + s1);
    }
    bf16x8 b[4][2];
#pragma unroll
    for (int nt = 0; nt < 4; ++nt)
#pragma unroll
      for (int z = 0; z < 2; ++z)
        b[nt][z] = *reinterpret_cast<const bf16x8*>(&Ks[cur][(nt * 16 + lr) * LDA + z * 32 + lg * 8]);

    f32x4 s[2][4] = {};
#pragma unroll
    for (int mt = 0; mt < 2; ++mt)
#pragma unroll
      for (int nt = 0; nt < 4; ++nt)
#pragma unroll
        for (int z = 0; z < 2; ++z)
          s[mt][nt] = __builtin_amdgcn_mfma_f32_16x16x32_bf16(aq[mt][z], b[nt][z], s[mt][nt], 0, 0, 0);

    // per-lane online update (scores already in base-2 units)
#pragma unroll
    for (int mt = 0; mt < 2; ++mt)
#pragma unroll
      for (int r = 0; r < 4; ++r) {
        float v0 = s[mt][0][r], v1 = s[mt][1][r], v2 = s[mt][2][r], v3 = s[mt][3][r];
        float cm = fmaxf(fmaxf(v0, v1), fmaxf(v2, v3));
        float mn = fmaxf(m[mt][r], cm);
        float p = exp2g(v0 - mn) + exp2g(v1 - mn) +
                  exp2g(v2 - mn) + exp2g(v3 - mn);
        l[mt][r] = l[mt][r] * exp2g(m[mt][r] - mn) + p;
        m[mt][r] = mn;
      }
    if (ci < NCH - 1) {
      *reinterpret_cast<uint4*>(&Ks[cur ^ 1][r0 * LDA + s0]) = n0;
      *reinterpret_cast<uint4*>(&Ks[cur ^ 1][r1 * LDA + s1]) = n1;
      __syncthreads();
    }
  }
  // butterfly merge across the 16 lr-lanes (lg bits untouched)
#pragma unroll
  for (int msk = 1; msk <= 8; msk <<= 1) {
#pragma unroll
    for (int mt = 0; mt < 2; ++mt)
#pragma unroll
      for (int r = 0; r < 4; ++r) {
        float mo = __shfl_xor(m[mt][r], msk);
        float lo = __shfl_xor(l[mt][r], msk);
        float mn = fmaxf(m[mt][r], mo);
        l[mt][r] = l[mt][r] * exp2g(m[mt][r] - mn) + lo * exp2g(mo - mn);
        m[mt][r] = mn;
      }
  }
  if (lr == 0) {
#pragma unroll
    for (int mt = 0; mt < 2; ++mt)
#pragma unroll
      for (int r = 0; r < 4; ++r) {
        int q = q0 + wave * 32 + mt * 16 + lg * 4 + r;
        part[(sp * HH + h) * NN + q] = make_float2(m[mt][r], l[mt][r]);
      }
  }
}

// ---------------- Kernel 4: merge splits + global sum ------------------------
// 24 blocks x 1024 thr, one row each; out was zeroed by convert_kernel.
__global__ __launch_bounds__(1024) void reduce_kernel(
    const float2* __restrict__ part, float* __restrict__ out) {
  const int t = threadIdx.x;
  const int row = blockIdx.x * 1024 + t;         // 0..24575 = (h*2048+q)
  float2 p0 = part[row];
  float2 p1 = part[NROWS + row];
  float2 p2 = part[2 * NROWS + row];
  float2 p3 = part[3 * NROWS + row];
  float mm = fmaxf(fmaxf(p0.x, p1.x), fmaxf(p2.x, p3.x));
  float ll = p0.y * exp2g(p0.x - mm) + p1.y * exp2g(p1.x - mm) +
             p2.y * exp2g(p2.x - mm) + p3.y * exp2g(p3.x - mm);
  float lse = mm + log2g(ll);                    // base-2 lse
#pragma unroll
  for (int msk = 1; msk <= 32; msk <<= 1)
    lse += __shfl_xor(lse, msk);
  __shared__ float wsum[16];
  if ((t & 63) == 0) wsum[t >> 6] = lse;
  __syncthreads();
  if (t == 0) {
    float s = 0.0f;
#pragma unroll
    for (int i = 0; i < 16; ++i) s += wsum[i];
    atomicAdd(out, -5.545177444479562f * s);     // -(1/beta)*ln2 * sum(lse2)
  }
}

// ---------------- launch -----------------------------------------------------
extern "C" void kernel_launch(void* const* d_in, const int* in_sizes, int n_in,
                              void* d_out, int out_size, void* d_ws, size_t ws_size,
                              hipStream_t stream) {
  const float* g  = (const float*)d_in[0];
  const float* Wq = (const float*)d_in[1];
  const float* Wk = (const float*)d_in[2];
  float* out = (float*)d_out;

  __hip_bfloat16* gB = (__hip_bfloat16*)d_ws;        // [2048][768]  (3.1 MB)
  __hip_bfloat16* wB = gB + G_ELEMS;                 // [1536][768]  (2.4 MB)
  __hip_bfloat16* QK = wB + 2 * W1_ELEMS;            // [2048][1536] (6.3 MB)
  // partials alias gB: gB is dead after proj_kernel (stream-ordered); 786 KB.
  float2* part = (float2*)gB;

  convert_kernel<<<2688, 256, 0, stream>>>(g, Wq, Wk, gB, wB, out);
  proj_kernel<<<384, 256, 0, stream>>>(gB, wB, QK);
  attn_kernel<<<dim3(16, HH, SPLITS), 256, 0, stream>>>(QK, part);
  reduce_kernel<<<24, 1024, 0, stream>>>(part, out);
}